// Round 4
// baseline (85.968 us; speedup 1.0000x reference)
//
#include <hip/hip_runtime.h>

// CustomBatchNorm2D forward, single-pass: x is read from HBM exactly once,
// held in registers across a hand-rolled device-wide barrier.
//
// x (N=32, C=512, H=32, W=32) f32.
//   S[i,c]  = sum_hw x[i,c,:]
//   mean[c] = sum_i S[i,c] / (N*HW)
//   diag[c] = sum_i (S[i,c] - HW*mean[c])^2 / HW
//   out     = A[c]*x + B[c],  A = gamma[c]*abs(diag[c]),  B = beta[c] - A*mean[c]
//
// Grid: 512 blocks x 256 threads, 32 rows/block (same sample, 32 consecutive
// channels). Each thread holds 32 float4 = 128 data VGPRs.
// Deadlock safety: __launch_bounds__(256,3) caps VGPR <= ~168 -> >=3 blocks/CU
// hardware capacity = 768 block slots >= 512 grid, so all blocks co-reside
// under a normal launch. Spin is bounded (~50ms) so failure = wrong answer,
// never a hang.

#define HW_   1024
#define C_    512
#define N_    32
#define RPB   32
#define NBLK  ((N_ * C_) / RPB)   // 512

__global__ void __launch_bounds__(256, 3)
fused_bn(const float* __restrict__ x,
         const float* __restrict__ gamma,
         const float* __restrict__ beta,
         float* __restrict__ out,
         float* __restrict__ S,
         unsigned int* __restrict__ cnt) {
    const int t    = threadIdx.x;
    const int b    = blockIdx.x;
    const int lane = t & 63;
    const int wid  = t >> 6;
    const int row0 = b * RPB;              // 32 rows, same sample
    const int c0   = row0 & (C_ - 1);      // first channel

    // ---- phase 1: load x into registers, per-row block sums ----
    const float4* xv = reinterpret_cast<const float4*>(x)
                       + (size_t)row0 * (HW_ / 4) + t;
    float4 d[RPB];
    #pragma unroll
    for (int j = 0; j < RPB; ++j)
        d[j] = xv[j * (HW_ / 4)];

    __shared__ float part[RPB][4];
    #pragma unroll
    for (int j = 0; j < RPB; ++j) {
        float s = (d[j].x + d[j].y) + (d[j].z + d[j].w);
        #pragma unroll
        for (int off = 32; off > 0; off >>= 1)
            s += __shfl_down(s, off, 64);
        if (lane == 0) part[j][wid] = s;
    }
    __syncthreads();
    if (t < RPB)
        S[row0 + t] = (part[t][0] + part[t][1]) + (part[t][2] + part[t][3]);

    // ---- device-wide barrier (release fence + atomic count + bounded spin) ----
    __syncthreads();
    if (t == 0) {
        __threadfence();                   // release S stores device-wide
        atomicAdd(cnt, 1u);
        int spins = 0;
        while (__hip_atomic_load(cnt, __ATOMIC_RELAXED, __HIP_MEMORY_SCOPE_AGENT)
                   < (unsigned)NBLK
               && spins < (1 << 18)) {     // bounded: ~50ms worst case
            __builtin_amdgcn_s_sleep(8);
            ++spins;
        }
    }
    __syncthreads();
    __threadfence();                       // acquire side

    // ---- phase 2: per-channel stats for this block's 32 channels ----
    __shared__ float Av[RPB], Bv[RPB];
    if (t < RPB) {
        const int c = c0 + t;
        float tot = 0.f;
        #pragma unroll
        for (int i = 0; i < N_; ++i) tot += S[i * C_ + c];
        const float mean  = tot * (1.0f / (float)(N_ * HW_));
        const float m1024 = tot * (1.0f / (float)N_);     // HW * mean
        float dd = 0.f;
        #pragma unroll
        for (int i = 0; i < N_; ++i) {
            const float e = S[i * C_ + c] - m1024;
            dd += e * e;
        }
        const float diag = dd * (1.0f / (float)HW_);
        const float A = gamma[c] * fabsf(diag);
        Av[t] = A;
        Bv[t] = beta[c] - A * mean;
    }
    __syncthreads();

    // ---- phase 3: apply affine from registers, store ----
    float4* ov = reinterpret_cast<float4*>(out)
                 + (size_t)row0 * (HW_ / 4) + t;
    #pragma unroll
    for (int j = 0; j < RPB; ++j) {
        const float A = Av[j], B = Bv[j];
        float4 o;
        o.x = fmaf(A, d[j].x, B);
        o.y = fmaf(A, d[j].y, B);
        o.z = fmaf(A, d[j].z, B);
        o.w = fmaf(A, d[j].w, B);
        ov[j * (HW_ / 4)] = o;
    }
}

extern "C" void kernel_launch(void* const* d_in, const int* in_sizes, int n_in,
                              void* d_out, int out_size, void* d_ws, size_t ws_size,
                              hipStream_t stream) {
    const float* x     = (const float*)d_in[0];
    const float* gamma = (const float*)d_in[1];
    const float* beta  = (const float*)d_in[2];
    float*       out   = (float*)d_out;

    float*        S   = (float*)d_ws;                       // 16384 floats
    unsigned int* cnt = (unsigned int*)((char*)d_ws + 65536);

    hipMemsetAsync(cnt, 0, sizeof(unsigned int), stream);
    fused_bn<<<NBLK, 256, 0, stream>>>(x, gamma, beta, out, S, cnt);
    (void)in_sizes; (void)n_in; (void)out_size; (void)ws_size;
}

// Round 5
// 30.601 us; speedup vs baseline: 2.8093x; 2.8093x over previous
//
#include <hip/hip_runtime.h>

// CustomBatchNorm2D forward — single kernel, single pass over x.
// x (N=32, C=512, H=32, W=32) f32.
//   S[i,c]  = sum_hw x[i,c,:]
//   mean[c] = sum_i S[i,c] / (N*HW)
//   diag[c] = sum_i (S[i,c] - HW*mean[c])^2 / HW
//   out     = A[c]*x + B[c],  A = gamma[c]*abs(diag[c]),  B = beta[c] - A*mean[c]
//
// Key insight: channel c's stats need ONLY x[:, c, :, :] (32 rows x 4 KB =
// 128 KB). One block per channel holds that in registers (8 float4/thread at
// 1024 threads), reduces block-locally, and applies — no second pass over x,
// no device-wide barrier, no LDS staging of data.

#define HW_   1024
#define C_    512
#define N_    32
#define KSTR  ((size_t)(4 * C_) * (HW_ / 4))   // float4 stride for +4 samples

__global__ void __launch_bounds__(1024)
bn_onepass(const float* __restrict__ x,
           const float* __restrict__ gamma,
           const float* __restrict__ beta,
           float* __restrict__ out) {
    const int c    = blockIdx.x;          // channel
    const int t    = threadIdx.x;
    const int lane = t & 63;
    const int wv   = t >> 6;              // wave 0..15
    const int rb   = t >> 8;              // base row 0..3
    const int pos  = t & 255;             // float4 position within row

    // thread t covers rows rb+4k (k=0..7), float4 slot `pos` of each.
    const size_t base = (((size_t)(rb * C_ + c)) << 8) + pos;

    const float4* xv = reinterpret_cast<const float4*>(x);
    float4 d[8];
    #pragma unroll
    for (int k = 0; k < 8; ++k)
        d[k] = xv[base + (size_t)k * KSTR];

    // Pin the loaded values in VGPRs: the asm "modifies" them, so the
    // compiler cannot rematerialize the loads for the apply phase.
    #pragma unroll
    for (int k = 0; k < 8; ++k)
        asm volatile("" : "+v"(d[k].x), "+v"(d[k].y), "+v"(d[k].z), "+v"(d[k].w));

    // per-row sums: each wave's 64 lanes share one row; 4 waves per row.
    __shared__ float part[N_][4];
    #pragma unroll
    for (int k = 0; k < 8; ++k) {
        float s = (d[k].x + d[k].y) + (d[k].z + d[k].w);
        #pragma unroll
        for (int off = 32; off > 0; off >>= 1)
            s += __shfl_down(s, off, 64);
        if (lane == 0) part[rb + 4 * k][wv & 3] = s;
    }
    __syncthreads();

    __shared__ float Sl[N_];
    if (t < N_)
        Sl[t] = (part[t][0] + part[t][1]) + (part[t][2] + part[t][3]);
    __syncthreads();

    // every thread computes A,B redundantly (uniform LDS broadcast, cheap)
    float tot = 0.f;
    #pragma unroll
    for (int i = 0; i < N_; ++i) tot += Sl[i];
    const float mean  = tot * (1.0f / (float)(N_ * HW_));
    const float m1024 = tot * (1.0f / (float)N_);   // HW * mean
    float dd = 0.f;
    #pragma unroll
    for (int i = 0; i < N_; ++i) {
        const float e = Sl[i] - m1024;
        dd += e * e;
    }
    const float diag = dd * (1.0f / (float)HW_);
    const float A = gamma[c] * fabsf(diag);
    const float B = beta[c] - A * mean;

    float4* ov = reinterpret_cast<float4*>(out);
    #pragma unroll
    for (int k = 0; k < 8; ++k) {
        float4 o;
        o.x = fmaf(A, d[k].x, B);
        o.y = fmaf(A, d[k].y, B);
        o.z = fmaf(A, d[k].z, B);
        o.w = fmaf(A, d[k].w, B);
        ov[base + (size_t)k * KSTR] = o;
    }
}

extern "C" void kernel_launch(void* const* d_in, const int* in_sizes, int n_in,
                              void* d_out, int out_size, void* d_ws, size_t ws_size,
                              hipStream_t stream) {
    const float* x     = (const float*)d_in[0];
    const float* gamma = (const float*)d_in[1];
    const float* beta  = (const float*)d_in[2];
    float*       out   = (float*)d_out;

    bn_onepass<<<C_, 1024, 0, stream>>>(x, gamma, beta, out);
    (void)in_sizes; (void)n_in; (void)out_size; (void)d_ws; (void)ws_size;
}

// Round 6
// 27.239 us; speedup vs baseline: 3.1561x; 1.1234x over previous
//
#include <hip/hip_runtime.h>

// CustomBatchNorm2D forward — single pass over x, software-pipelined 2
// channels per block.
// x (N=32, C=512, H=32, W=32) f32.
//   S[i,c]  = sum_hw x[i,c,:]
//   mean[c] = sum_i S[i,c] / (N*HW)
//   diag[c] = sum_i (S[i,c] - HW*mean[c])^2 / HW
//   out     = A[c]*x + B[c],  A = gamma[c]*abs(diag[c]),  B = beta[c] - A*mean[c]
//
// Grid: 256 blocks x 1024 threads == exactly 1 block per CU, all resident.
// Block b owns channels c0=b and c1=b+256 (128 KB each, in registers:
// 8 float4/thread/channel). Pipeline: load c0 | reduce c0 | issue c1 loads |
// stats0 | store c0 (overlaps c1 read stream) | reduce c1 | stats1 | store c1.
//
// Row mapping: 32 samples/channel; thread t -> row r = t>>5 (one row per
// 32-lane half-wave), slot j = t&31; covers float4 q = k*32+j, k=0..7.

#define HW_   1024
#define C_    512
#define N_    32

__global__ void __launch_bounds__(1024)
bn_pipe2(const float* __restrict__ x,
         const float* __restrict__ gamma,
         const float* __restrict__ beta,
         float* __restrict__ out) {
    const int t  = threadIdx.x;
    const int r  = t >> 5;          // sample/row 0..31
    const int j  = t & 31;          // float4 slot base within row
    const int c0 = blockIdx.x;
    const int c1 = c0 + 256;

    const float4* xv = reinterpret_cast<const float4*>(x);
    float4*       ov = reinterpret_cast<float4*>(out);

    const size_t base0 = (((size_t)(r * C_ + c0)) << 8) + j;
    const size_t base1 = (((size_t)(r * C_ + c1)) << 8) + j;

    __shared__ float Sl0[N_], Sl1[N_];

    // ---- load c0 ----
    float4 d0[8];
    #pragma unroll
    for (int k = 0; k < 8; ++k) d0[k] = xv[base0 + k * 32];
    #pragma unroll
    for (int k = 0; k < 8; ++k)
        asm volatile("" : "+v"(d0[k].x), "+v"(d0[k].y), "+v"(d0[k].z), "+v"(d0[k].w));

    // ---- reduce c0: per-thread sum, then 32-lane half-wave reduce ----
    {
        float s = 0.f;
        #pragma unroll
        for (int k = 0; k < 8; ++k)
            s += (d0[k].x + d0[k].y) + (d0[k].z + d0[k].w);
        #pragma unroll
        for (int off = 16; off > 0; off >>= 1)
            s += __shfl_xor(s, off, 64);    // offs <32 stay within half-wave
        if (j == 0) Sl0[r] = s;
    }

    // ---- issue c1 loads (in flight across stats0 + store c0) ----
    float4 d1[8];
    #pragma unroll
    for (int k = 0; k < 8; ++k) d1[k] = xv[base1 + k * 32];
    #pragma unroll
    for (int k = 0; k < 8; ++k)
        asm volatile("" : "+v"(d1[k].x), "+v"(d1[k].y), "+v"(d1[k].z), "+v"(d1[k].w));

    __syncthreads();

    // ---- stats c0 (redundant per thread; uniform LDS broadcast reads) ----
    float A0, B0;
    {
        float tot = 0.f;
        #pragma unroll
        for (int i = 0; i < N_; ++i) tot += Sl0[i];
        const float mean  = tot * (1.0f / (float)(N_ * HW_));
        const float m1024 = tot * (1.0f / (float)N_);
        float dd = 0.f;
        #pragma unroll
        for (int i = 0; i < N_; ++i) {
            const float e = Sl0[i] - m1024;
            dd += e * e;
        }
        const float diag = dd * (1.0f / (float)HW_);
        A0 = gamma[c0] * fabsf(diag);
        B0 = beta[c0] - A0 * mean;
    }

    // ---- store c0 ----
    #pragma unroll
    for (int k = 0; k < 8; ++k) {
        float4 o;
        o.x = fmaf(A0, d0[k].x, B0);
        o.y = fmaf(A0, d0[k].y, B0);
        o.z = fmaf(A0, d0[k].z, B0);
        o.w = fmaf(A0, d0[k].w, B0);
        ov[base0 + k * 32] = o;
    }

    // ---- reduce c1 ----
    {
        float s = 0.f;
        #pragma unroll
        for (int k = 0; k < 8; ++k)
            s += (d1[k].x + d1[k].y) + (d1[k].z + d1[k].w);
        #pragma unroll
        for (int off = 16; off > 0; off >>= 1)
            s += __shfl_xor(s, off, 64);
        if (j == 0) Sl1[r] = s;
    }
    __syncthreads();

    // ---- stats c1 ----
    float A1, B1;
    {
        float tot = 0.f;
        #pragma unroll
        for (int i = 0; i < N_; ++i) tot += Sl1[i];
        const float mean  = tot * (1.0f / (float)(N_ * HW_));
        const float m1024 = tot * (1.0f / (float)N_);
        float dd = 0.f;
        #pragma unroll
        for (int i = 0; i < N_; ++i) {
            const float e = Sl1[i] - m1024;
            dd += e * e;
        }
        const float diag = dd * (1.0f / (float)HW_);
        A1 = gamma[c1] * fabsf(diag);
        B1 = beta[c1] - A1 * mean;
    }

    // ---- store c1 ----
    #pragma unroll
    for (int k = 0; k < 8; ++k) {
        float4 o;
        o.x = fmaf(A1, d1[k].x, B1);
        o.y = fmaf(A1, d1[k].y, B1);
        o.z = fmaf(A1, d1[k].z, B1);
        o.w = fmaf(A1, d1[k].w, B1);
        ov[base1 + k * 32] = o;
    }
}

extern "C" void kernel_launch(void* const* d_in, const int* in_sizes, int n_in,
                              void* d_out, int out_size, void* d_ws, size_t ws_size,
                              hipStream_t stream) {
    const float* x     = (const float*)d_in[0];
    const float* gamma = (const float*)d_in[1];
    const float* beta  = (const float*)d_in[2];
    float*       out   = (float*)d_out;

    bn_pipe2<<<256, 1024, 0, stream>>>(x, gamma, beta, out);
    (void)in_sizes; (void)n_in; (void)out_size; (void)d_ws; (void)ws_size;
}

// Round 7
// 26.761 us; speedup vs baseline: 3.2125x; 1.0179x over previous
//
#include <hip/hip_runtime.h>

// CustomBatchNorm2D forward — single pass over x, one channel per block,
// 2 blocks resident per CU for hardware-scheduled load/store overlap.
//
// x (N=32, C=512, H=32, W=32) f32.
//   S[i,c]  = sum_hw x[i,c,:]
//   mean[c] = sum_i S[i,c] / (N*HW)
//   diag[c] = sum_i (S[i,c] - HW*mean[c])^2 / HW
//   out     = A[c]*x + B[c],  A = gamma[c]*abs(diag[c]),  B = beta[c] - A*mean[c]
//
// Grid: 512 blocks x 512 threads. Block = one channel = 32 rows x 4 KB
// = 128 KB held in registers (16 float4/thread = 64 data VGPRs).
// __launch_bounds__(512,4): 4 waves/SIMD min -> VGPR cap 128 -> 2 blocks/CU
// co-resident; the two blocks drift out of phase, overlapping one block's
// stores with the other's loads without any explicit software pipeline.
//
// Thread map: t -> row r = t>>4 (16 lanes per row), slot j = t&15;
// thread covers float4 slots j + 16k, k = 0..15 of row r.

#define HW_   1024
#define C_    512
#define N_    32

__global__ void __launch_bounds__(512, 4)
bn_chan(const float* __restrict__ x,
        const float* __restrict__ gamma,
        const float* __restrict__ beta,
        float* __restrict__ out) {
    const int t = threadIdx.x;
    const int r = t >> 4;           // row/sample 0..31
    const int j = t & 15;           // float4 slot base
    const int c = blockIdx.x;       // channel

    const float4* xv = reinterpret_cast<const float4*>(x);
    float4*       ov = reinterpret_cast<float4*>(out);
    const size_t base = (((size_t)(r * C_ + c)) << 8) + j;   // float4 index

    // ---- load the channel into registers ----
    float4 d[16];
    #pragma unroll
    for (int k = 0; k < 16; ++k)
        d[k] = xv[base + k * 16];

    // Pin: prevents the allocator from rematerializing these loads for the
    // store phase (round-4 failure mode).
    #pragma unroll
    for (int k = 0; k < 16; ++k)
        asm volatile("" : "+v"(d[k].x), "+v"(d[k].y), "+v"(d[k].z), "+v"(d[k].w));

    // ---- per-row sum: per-thread then 16-lane-group butterfly ----
    float s = 0.f;
    #pragma unroll
    for (int k = 0; k < 16; ++k)
        s += (d[k].x + d[k].y) + (d[k].z + d[k].w);
    #pragma unroll
    for (int off = 8; off > 0; off >>= 1)
        s += __shfl_xor(s, off, 64);         // stays within the 16-lane group

    __shared__ float Sl[N_];
    if (j == 0) Sl[r] = s;
    __syncthreads();

    // ---- stats (redundant per thread; uniform LDS broadcasts) ----
    float tot = 0.f;
    #pragma unroll
    for (int i = 0; i < N_; ++i) tot += Sl[i];
    const float mean  = tot * (1.0f / (float)(N_ * HW_));
    const float m1024 = tot * (1.0f / (float)N_);   // HW * mean
    float dd = 0.f;
    #pragma unroll
    for (int i = 0; i < N_; ++i) {
        const float e = Sl[i] - m1024;
        dd += e * e;
    }
    const float diag = dd * (1.0f / (float)HW_);
    const float A = gamma[c] * fabsf(diag);
    const float B = beta[c] - A * mean;

    // ---- apply + store from registers ----
    #pragma unroll
    for (int k = 0; k < 16; ++k) {
        float4 o;
        o.x = fmaf(A, d[k].x, B);
        o.y = fmaf(A, d[k].y, B);
        o.z = fmaf(A, d[k].z, B);
        o.w = fmaf(A, d[k].w, B);
        ov[base + k * 16] = o;
    }
}

extern "C" void kernel_launch(void* const* d_in, const int* in_sizes, int n_in,
                              void* d_out, int out_size, void* d_ws, size_t ws_size,
                              hipStream_t stream) {
    const float* x     = (const float*)d_in[0];
    const float* gamma = (const float*)d_in[1];
    const float* beta  = (const float*)d_in[2];
    float*       out   = (float*)d_out;

    bn_chan<<<C_, 512, 0, stream>>>(x, gamma, beta, out);
    (void)in_sizes; (void)n_in; (void)out_size; (void)d_ws; (void)ws_size;
}

// Round 8
// 25.947 us; speedup vs baseline: 3.3133x; 1.0314x over previous
//
#include <hip/hip_runtime.h>

// CustomBatchNorm2D forward — single pass over x, 2 channels per block,
// software-pipelined so the c0 STORE stream overlaps the c1 LOAD stream.
//
// x (N=32, C=512, H=32, W=32) f32.
//   S[i,c]  = sum_hw x[i,c,:]
//   mean[c] = sum_i S[i,c] / (N*HW)
//   diag[c] = sum_i (S[i,c] - HW*mean[c])^2 / HW
//   out     = A[c]*x + B[c],  A = gamma[c]*abs(diag[c]),  B = beta[c] - A*mean[c]
//
// Grid: 256 blocks x 1024 threads = 1 block/CU, all resident.
// Block b owns channels c0=b, c1=b+256; 8 float4/thread/channel.
// KEY vs round 6: the d1 register-pin (which forces a vmcnt drain) is AFTER
// the c0 store loop, so c1's global loads stay in flight underneath the c0
// stores — genuine R/W overlap in the memory system. (Round 6 pinned d1
// before the barrier, serializing read-then-write chip-wide.)
//
// Thread map: t -> row r = t>>5 (32 lanes per row), slot j = t&31;
// thread covers float4 slots j + 32k, k = 0..7.

#define HW_   1024
#define C_    512
#define N_    32

__global__ void __launch_bounds__(1024)
bn_pipe2b(const float* __restrict__ x,
          const float* __restrict__ gamma,
          const float* __restrict__ beta,
          float* __restrict__ out) {
    const int t  = threadIdx.x;
    const int r  = t >> 5;          // sample/row 0..31
    const int j  = t & 31;          // float4 slot base within row
    const int c0 = blockIdx.x;
    const int c1 = c0 + 256;

    const float4* xv = reinterpret_cast<const float4*>(x);
    float4*       ov = reinterpret_cast<float4*>(out);

    const size_t base0 = (((size_t)(r * C_ + c0)) << 8) + j;
    const size_t base1 = (((size_t)(r * C_ + c1)) << 8) + j;

    __shared__ float Sl0[N_], Sl1[N_];

    // ---- load c0 and pin (pin needed before reduce anyway) ----
    float4 d0[8];
    #pragma unroll
    for (int k = 0; k < 8; ++k) d0[k] = xv[base0 + k * 32];
    #pragma unroll
    for (int k = 0; k < 8; ++k)
        asm volatile("" : "+v"(d0[k].x), "+v"(d0[k].y), "+v"(d0[k].z), "+v"(d0[k].w));

    // ---- reduce c0 ----
    {
        float s = 0.f;
        #pragma unroll
        for (int k = 0; k < 8; ++k)
            s += (d0[k].x + d0[k].y) + (d0[k].z + d0[k].w);
        #pragma unroll
        for (int off = 16; off > 0; off >>= 1)
            s += __shfl_xor(s, off, 64);    // stays within 32-lane group
        if (j == 0) Sl0[r] = s;
    }

    // ---- ISSUE c1 loads; do NOT pin yet (no vmcnt drain here) ----
    float4 d1[8];
    #pragma unroll
    for (int k = 0; k < 8; ++k) d1[k] = xv[base1 + k * 32];

    __syncthreads();

    // ---- stats c0 ----
    float A0, B0;
    {
        float tot = 0.f;
        #pragma unroll
        for (int i = 0; i < N_; ++i) tot += Sl0[i];
        const float mean  = tot * (1.0f / (float)(N_ * HW_));
        const float m1024 = tot * (1.0f / (float)N_);
        float dd = 0.f;
        #pragma unroll
        for (int i = 0; i < N_; ++i) {
            const float e = Sl0[i] - m1024;
            dd += e * e;
        }
        const float diag = dd * (1.0f / (float)HW_);
        A0 = gamma[c0] * fabsf(diag);
        B0 = beta[c0] - A0 * mean;
    }

    // ---- store c0 (c1 loads still streaming in behind these stores) ----
    #pragma unroll
    for (int k = 0; k < 8; ++k) {
        float4 o;
        o.x = fmaf(A0, d0[k].x, B0);
        o.y = fmaf(A0, d0[k].y, B0);
        o.z = fmaf(A0, d0[k].z, B0);
        o.w = fmaf(A0, d0[k].w, B0);
        ov[base0 + k * 32] = o;
    }

    // ---- NOW pin d1 (drains c1 loads after the c0 stores are issued) ----
    #pragma unroll
    for (int k = 0; k < 8; ++k)
        asm volatile("" : "+v"(d1[k].x), "+v"(d1[k].y), "+v"(d1[k].z), "+v"(d1[k].w));

    // ---- reduce c1 ----
    {
        float s = 0.f;
        #pragma unroll
        for (int k = 0; k < 8; ++k)
            s += (d1[k].x + d1[k].y) + (d1[k].z + d1[k].w);
        #pragma unroll
        for (int off = 16; off > 0; off >>= 1)
            s += __shfl_xor(s, off, 64);
        if (j == 0) Sl1[r] = s;
    }
    __syncthreads();

    // ---- stats c1 ----
    float A1, B1;
    {
        float tot = 0.f;
        #pragma unroll
        for (int i = 0; i < N_; ++i) tot += Sl1[i];
        const float mean  = tot * (1.0f / (float)(N_ * HW_));
        const float m1024 = tot * (1.0f / (float)N_);
        float dd = 0.f;
        #pragma unroll
        for (int i = 0; i < N_; ++i) {
            const float e = Sl1[i] - m1024;
            dd += e * e;
        }
        const float diag = dd * (1.0f / (float)HW_);
        A1 = gamma[c1] * fabsf(diag);
        B1 = beta[c1] - A1 * mean;
    }

    // ---- store c1 ----
    #pragma unroll
    for (int k = 0; k < 8; ++k) {
        float4 o;
        o.x = fmaf(A1, d1[k].x, B1);
        o.y = fmaf(A1, d1[k].y, B1);
        o.z = fmaf(A1, d1[k].z, B1);
        o.w = fmaf(A1, d1[k].w, B1);
        ov[base1 + k * 32] = o;
    }
}

extern "C" void kernel_launch(void* const* d_in, const int* in_sizes, int n_in,
                              void* d_out, int out_size, void* d_ws, size_t ws_size,
                              hipStream_t stream) {
    const float* x     = (const float*)d_in[0];
    const float* gamma = (const float*)d_in[1];
    const float* beta  = (const float*)d_in[2];
    float*       out   = (float*)d_out;

    bn_pipe2b<<<256, 1024, 0, stream>>>(x, gamma, beta, out);
    (void)in_sizes; (void)n_in; (void)out_size; (void)d_ws; (void)ws_size;
}

// Round 9
// 24.745 us; speedup vs baseline: 3.4741x; 1.0485x over previous
//
#include <hip/hip_runtime.h>

// CustomBatchNorm2D forward — single pass over x, 2 channels per block,
// genuinely overlapped R/W streams.
//
// x (N=32, C=512, H=32, W=32) f32.
//   S[i,c]  = sum_hw x[i,c,:]
//   mean[c] = sum_i S[i,c] / (N*HW)
//   diag[c] = sum_i (S[i,c] - HW*mean[c])^2 / HW
//   out     = A[c]*x + B[c],  A = gamma[c]*abs(diag[c]),  B = beta[c] - A*mean[c]
//
// Round-8 post-mortem: __syncthreads() emits s_waitcnt vmcnt(0) before
// s_barrier, draining the in-flight c1 loads -> chip ran serial R then W.
// This version:
//   * ALL 16 loads (c0+c1) issued at the top (continuous read stream),
//   * raw s_barrier + lgkmcnt(0)-only wait (LDS sync WITHOUT vmcnt drain),
//   * d1 pin (the only vmcnt wait on c1) placed after the c0 stores,
//   * nontemporal loads/stores (pure streaming, zero reuse).
//
// Grid: 256 blocks x 1024 threads = 1 block/CU. Thread map: row r = t>>5
// (32 lanes per row), float4 slots j + 32k, k=0..7.

#define HW_   1024
#define C_    512
#define N_    32

typedef float f4 __attribute__((ext_vector_type(4)));

__global__ void __launch_bounds__(1024)
bn_pipe3(const float* __restrict__ x,
         const float* __restrict__ gamma,
         const float* __restrict__ beta,
         float* __restrict__ out) {
    const int t  = threadIdx.x;
    const int r  = t >> 5;          // sample/row 0..31
    const int j  = t & 31;          // float4 slot base within row
    const int c0 = blockIdx.x;
    const int c1 = c0 + 256;

    const f4* xv = reinterpret_cast<const f4*>(x);
    f4*       ov = reinterpret_cast<f4*>(out);
    const size_t base0 = (((size_t)(r * C_ + c0)) << 8) + j;
    const size_t base1 = (((size_t)(r * C_ + c1)) << 8) + j;

    __shared__ float Sl0[N_], Sl1[N_];

    // ---- issue ALL loads up front: continuous chip-wide read stream ----
    f4 d0[8], d1[8];
    #pragma unroll
    for (int k = 0; k < 8; ++k)
        d0[k] = __builtin_nontemporal_load(xv + base0 + k * 32);
    #pragma unroll
    for (int k = 0; k < 8; ++k)
        d1[k] = __builtin_nontemporal_load(xv + base1 + k * 32);
    __builtin_amdgcn_sched_barrier(0);   // keep the load cluster here

    // pin d0 (counted waits; also blocks rematerialization of the loads)
    #pragma unroll
    for (int k = 0; k < 8; ++k)
        asm volatile("" : "+v"(d0[k]));

    // ---- reduce c0: per-thread sum, 32-lane-group butterfly ----
    {
        float s = 0.f;
        #pragma unroll
        for (int k = 0; k < 8; ++k)
            s += (d0[k].x + d0[k].y) + (d0[k].z + d0[k].w);
        #pragma unroll
        for (int off = 16; off > 0; off >>= 1)
            s += __shfl_xor(s, off, 64);     // stays within the 32-lane group
        if (j == 0) Sl0[r] = s;
    }

    // ---- LDS-only barrier: does NOT drain vmcnt (d1 stays in flight) ----
    asm volatile("s_waitcnt lgkmcnt(0)" ::: "memory");
    __builtin_amdgcn_s_barrier();

    // ---- stats c0 (redundant per thread; uniform LDS broadcasts) ----
    float A0, B0;
    {
        float tot = 0.f;
        #pragma unroll
        for (int i = 0; i < N_; ++i) tot += Sl0[i];
        const float mean  = tot * (1.0f / (float)(N_ * HW_));
        const float m1024 = tot * (1.0f / (float)N_);
        float dd = 0.f;
        #pragma unroll
        for (int i = 0; i < N_; ++i) {
            const float e = Sl0[i] - m1024;
            dd += e * e;
        }
        const float diag = dd * (1.0f / (float)HW_);
        A0 = gamma[c0] * fabsf(diag);
        B0 = beta[c0] - A0 * mean;
    }

    // ---- store c0 (c1 reads still streaming underneath) ----
    #pragma unroll
    for (int k = 0; k < 8; ++k) {
        f4 o;
        o.x = fmaf(A0, d0[k].x, B0);
        o.y = fmaf(A0, d0[k].y, B0);
        o.z = fmaf(A0, d0[k].z, B0);
        o.w = fmaf(A0, d0[k].w, B0);
        __builtin_nontemporal_store(o, ov + base0 + k * 32);
    }

    // ---- NOW consume d1 (counted vmcnt waits; most data already landed) ----
    #pragma unroll
    for (int k = 0; k < 8; ++k)
        asm volatile("" : "+v"(d1[k]));

    // ---- reduce c1 ----
    {
        float s = 0.f;
        #pragma unroll
        for (int k = 0; k < 8; ++k)
            s += (d1[k].x + d1[k].y) + (d1[k].z + d1[k].w);
        #pragma unroll
        for (int off = 16; off > 0; off >>= 1)
            s += __shfl_xor(s, off, 64);
        if (j == 0) Sl1[r] = s;
    }

    asm volatile("s_waitcnt lgkmcnt(0)" ::: "memory");
    __builtin_amdgcn_s_barrier();

    // ---- stats c1 ----
    float A1, B1;
    {
        float tot = 0.f;
        #pragma unroll
        for (int i = 0; i < N_; ++i) tot += Sl1[i];
        const float mean  = tot * (1.0f / (float)(N_ * HW_));
        const float m1024 = tot * (1.0f / (float)N_);
        float dd = 0.f;
        #pragma unroll
        for (int i = 0; i < N_; ++i) {
            const float e = Sl1[i] - m1024;
            dd += e * e;
        }
        const float diag = dd * (1.0f / (float)HW_);
        A1 = gamma[c1] * fabsf(diag);
        B1 = beta[c1] - A1 * mean;
    }

    // ---- store c1 ----
    #pragma unroll
    for (int k = 0; k < 8; ++k) {
        f4 o;
        o.x = fmaf(A1, d1[k].x, B1);
        o.y = fmaf(A1, d1[k].y, B1);
        o.z = fmaf(A1, d1[k].z, B1);
        o.w = fmaf(A1, d1[k].w, B1);
        __builtin_nontemporal_store(o, ov + base1 + k * 32);
    }
}

extern "C" void kernel_launch(void* const* d_in, const int* in_sizes, int n_in,
                              void* d_out, int out_size, void* d_ws, size_t ws_size,
                              hipStream_t stream) {
    const float* x     = (const float*)d_in[0];
    const float* gamma = (const float*)d_in[1];
    const float* beta  = (const float*)d_in[2];
    float*       out   = (float*)d_out;

    bn_pipe3<<<256, 1024, 0, stream>>>(x, gamma, beta, out);
    (void)in_sizes; (void)n_in; (void)out_size; (void)d_ws; (void)ws_size;
}